// Round 3
// baseline (521.121 us; speedup 1.0000x reference)
//
#include <hip/hip_runtime.h>
#include <hip/hip_bf16.h>

typedef short short8 __attribute__((ext_vector_type(8)));
typedef float f32x4 __attribute__((ext_vector_type(4)));

#define XSTRIDE 264  // bf16 elements per LDS row: 256 + 8 pad

static __device__ inline short f2bf(float f) {
    unsigned u = __float_as_uint(f);
    unsigned r = (u + 0x7fffu + ((u >> 16) & 1u)) >> 16;
    return (short)r;
}
static __device__ inline float bf2f(short s) {
    return __uint_as_float(((unsigned)(unsigned short)s) << 16);
}

// One prep dispatch:
//   idx <  32768 : Wu[idx] = W1a - W1c          (tgt-coefficient matrix, f32)
//   idx <  98304 : Wfrag repack (Wcat -> MFMA B-fragment order, bf16)
//   else         : zero d_out (2048*128 floats) for the atomic accumulation
// Wcat[k][n]: k<128 -> W1b[k][n]+W1c[k][n];  k>=128 -> W1d[k-128][n]
// Wfrag[((t*8+s)*64+l)*8+j] = Wcat[s*32 + (l>>4)*8 + j][t*16 + (l&15)]
__global__ void prep(const float* __restrict__ W1, float* __restrict__ Wu,
                     short* __restrict__ Wfrag, float* __restrict__ out) {
    int idx = blockIdx.x * 256 + threadIdx.x;           // grid: 1408*256 = 360448
    if (idx < 32768) {
        Wu[idx] = W1[idx] - W1[idx + 256 * 256];
    } else if (idx < 98304) {
        int i = idx - 32768;
        int j = i & 7;
        int l = (i >> 3) & 63;
        int s = (i >> 9) & 7;
        int t = i >> 12;
        int k = s * 32 + ((l >> 4) << 3) + j;
        int n = t * 16 + (l & 15);
        float v;
        if (k < 128) v = W1[(128 + k) * 256 + n] + W1[(256 + k) * 256 + n];
        else         v = W1[(384 + (k - 128)) * 256 + n];
        Wfrag[i] = f2bf(v);
    } else {
        out[idx - 98304] = 0.f;                         // 262144 floats = 2048*128
    }
}

// Main fused kernel: 2 blocks per batch element (L-tile halves); 4 waves each.
// U[j]        = b1[j] + target[b] @ Wu[:,j]                        (f32, fused)
// h_pre[l][j] = U[j] + X[l] @ Wcat[:,j], X[l]=[item[l], item[l]*tgt] (bf16 MFMA)
// score[l]    = relu(h_pre[l]) @ W2 + b2
// out[b][d]  += sum_{l in this block's tiles, l<slen} score[l]*item[l][d]  (atomic)
__launch_bounds__(256, 4)
__global__ void din_main(const float* __restrict__ target, const float* __restrict__ item_seq,
                         const int* __restrict__ seq_len, const float* __restrict__ W2,
                         const float* __restrict__ b2p, const short* __restrict__ Wfrag,
                         const float* __restrict__ Wu, const float* __restrict__ b1,
                         float* __restrict__ out) {
    const int bid = blockIdx.x;
    const int b = bid >> 1;
    const int half = bid & 1;
    const int tid = threadIdx.x;
    const int lane = tid & 63;
    const int wave = tid >> 6;
    const int col = lane & 15;   // MFMA C-layout col / B-frag n
    const int q = lane >> 4;     // quad: C rows q*4..q*4+3, A/B k-offset q*8

    const int slen = seq_len[b];
    const int nt = (slen + 15) >> 4;
    const int h0 = (nt + 1) >> 1;
    const int t0 = half ? h0 : 0;
    const int t1 = half ? nt : h0;
    if (t0 >= t1) return;        // uniform per block — safe early exit

    __shared__ __attribute__((aligned(16))) short Xl[16 * XSTRIDE];
    __shared__ __attribute__((aligned(16))) float tshared[128];
    __shared__ float u_s[256];
    __shared__ float w2_s[256];
    __shared__ float scoreP[4][16];
    __shared__ float out_s[128];

    const float b2 = b2p[0];

    // Staging assignment (fixed per thread): row r, cols c..c+7
    const int r = tid >> 4;
    const int c = (tid & 15) << 3;

    // ---- Prefetch first tile into registers (overlaps startup below) ----
    float4 v0, v1;
    {
        int lr = t0 * 16 + r;
        if (lr > 199) lr = 199;
        const float4* src = (const float4*)(item_seq + (((size_t)b * 200 + lr) * 128 + c));
        v0 = src[0]; v1 = src[1];
    }

    if (tid < 128) tshared[tid] = target[b * 128 + tid];
    w2_s[tid] = W2[tid];
    __syncthreads();

    // ---- Fused U: u_s[j] = b1[j] + sum_d tshared[d]*Wu[d*256+j] ----
    {
        float uacc = b1[tid];
#pragma unroll 8
        for (int d = 0; d < 128; ++d) uacc += tshared[d] * Wu[d * 256 + tid];
        u_s[tid] = uacc;
    }

    float tgt8[8];
    {
        const float4* t4 = (const float4*)(tshared + c);
        float4 ta = t4[0], tb = t4[1];
        tgt8[0] = ta.x; tgt8[1] = ta.y; tgt8[2] = ta.z; tgt8[3] = ta.w;
        tgt8[4] = tb.x; tgt8[5] = tb.y; tgt8[6] = tb.z; tgt8[7] = tb.w;
    }

    // ---- B fragments: this wave's 4 N-tiles × 8 K-steps, resident in registers ----
    short8 bfrag[4][8];
    {
        const short* base = Wfrag + ((size_t)(wave * 32) * 64 + lane) * 8;
#pragma unroll
        for (int i = 0; i < 4; i++)
#pragma unroll
            for (int s = 0; s < 8; s++)
                bfrag[i][s] = *(const short8*)(base + (size_t)((i * 8 + s) * 64) * 8);
    }

    float out_val = 0.f;
    f32x4 acc[4];

    for (int mt = t0; mt < t1; ++mt) {
        const int l0 = mt * 16;
        __syncthreads();  // previous tile's Xl readers done before restage

        // Pack prefetched registers -> Xl (item rows k 0..127, item*tgt k 128..255)
        {
            float v[8] = {v0.x, v0.y, v0.z, v0.w, v1.x, v1.y, v1.z, v1.w};
            short8 p0, p1;
#pragma unroll
            for (int i = 0; i < 8; i++) {
                p0[i] = f2bf(v[i]);
                p1[i] = f2bf(v[i] * tgt8[i]);
            }
            short* xr = Xl + r * XSTRIDE;
            *(short8*)(xr + c) = p0;
            *(short8*)(xr + 128 + c) = p1;
        }
        __syncthreads();

        // ---- Prefetch next tile (overlaps MFMA + epilogue) ----
        if (mt + 1 < t1) {
            int lr = l0 + 16 + r;
            if (lr > 199) lr = 199;     // clamped rows masked out later
            const float4* src = (const float4*)(item_seq + (((size_t)b * 200 + lr) * 128 + c));
            v0 = src[0]; v1 = src[1];
        }

#pragma unroll
        for (int i = 0; i < 4; i++) acc[i] = (f32x4){0.f, 0.f, 0.f, 0.f};

        const short* arow = Xl + col * XSTRIDE + q * 8;
#pragma unroll
        for (int s = 0; s < 8; s++) {
            short8 afrag = *(const short8*)(arow + s * 32);
#pragma unroll
            for (int i = 0; i < 4; i++)
                acc[i] = __builtin_amdgcn_mfma_f32_16x16x32_bf16(afrag, bfrag[i][s], acc[i], 0, 0, 0);
        }

        // Epilogue: relu + W2 partials. Lane holds (row=q*4+rg, col) of each tile.
        float sv[4] = {0.f, 0.f, 0.f, 0.f};
#pragma unroll
        for (int i = 0; i < 4; i++) {
            int j = (wave * 4 + i) * 16 + col;
            float uj = u_s[j], wj = w2_s[j];
#pragma unroll
            for (int rg = 0; rg < 4; rg++) {
                float h = acc[i][rg] + uj;
                h = h > 0.f ? h : 0.f;
                sv[rg] += h * wj;
            }
        }
#pragma unroll
        for (int off = 1; off < 16; off <<= 1) {
#pragma unroll
            for (int rg = 0; rg < 4; rg++) sv[rg] += __shfl_xor(sv[rg], off, 64);
        }
        if (col == 0) {
#pragma unroll
            for (int rg = 0; rg < 4; rg++) scoreP[wave][q * 4 + rg] = sv[rg];
        }
        __syncthreads();

        // out_val += sum_m score[m]*item[l0+m][d]; m-range split across thread halves
        {
            int d = tid & 127;
            int mbase = (tid >> 7) * 8;
#pragma unroll
            for (int mm = 0; mm < 8; mm++) {
                int m = mbase + mm;
                int l = l0 + m;
                float s = scoreP[0][m] + scoreP[1][m] + scoreP[2][m] + scoreP[3][m] + b2;
                s = (l < slen) ? s : 0.f;
                out_val += s * bf2f(Xl[m * XSTRIDE + d]);
            }
        }
    }

    __syncthreads();
    if (tid >= 128) out_s[tid - 128] = out_val;
    __syncthreads();
    if (tid < 128) atomicAdd(&out[b * 128 + tid], out_val + out_s[tid]);
}

extern "C" void kernel_launch(void* const* d_in, const int* in_sizes, int n_in,
                              void* d_out, int out_size, void* d_ws, size_t ws_size,
                              hipStream_t stream) {
    const float* target   = (const float*)d_in[0];
    const float* item_seq = (const float*)d_in[1];
    const int*   seq_len  = (const int*)d_in[2];
    const float* W1       = (const float*)d_in[3];
    const float* b1       = (const float*)d_in[4];
    const float* W2       = (const float*)d_in[5];
    const float* b2       = (const float*)d_in[6];
    float* out = (float*)d_out;

    char* ws = (char*)d_ws;
    float* Wu    = (float*)ws;                  // 128*256*4 = 131072 B
    short* Wfrag = (short*)(ws + 131072);       // 65536*2   = 131072 B

    prep<<<1408, 256, 0, stream>>>(W1, Wu, Wfrag, out);
    din_main<<<4096, 256, 0, stream>>>(target, item_seq, seq_len, W2, b2, Wfrag, Wu, b1, out);
}

// Round 4
// 349.752 us; speedup vs baseline: 1.4900x; 1.4900x over previous
//
#include <hip/hip_runtime.h>
#include <hip/hip_bf16.h>

typedef short short8 __attribute__((ext_vector_type(8)));
typedef float f32x4 __attribute__((ext_vector_type(4)));

#define XSTRIDE 264  // bf16 elements per LDS row: 256 + 8 pad

static __device__ inline short f2bf(float f) {
    unsigned u = __float_as_uint(f);
    unsigned r = (u + 0x7fffu + ((u >> 16) & 1u)) >> 16;
    return (short)r;
}
static __device__ inline float bf2f(short s) {
    return __uint_as_float(((unsigned)(unsigned short)s) << 16);
}

// One prep dispatch:
//   idx <  32768 : Wu[idx] = W1a - W1c          (tgt-coefficient matrix, f32)
//   idx <  98304 : Wfrag repack (Wcat -> MFMA B-fragment order, bf16)
//   else         : zero d_out (2048*128 floats) for the atomic accumulation
// Wcat[k][n]: k<128 -> W1b[k][n]+W1c[k][n];  k>=128 -> W1d[k-128][n]
// Wfrag[((t*8+s)*64+l)*8+j] = Wcat[s*32 + (l>>4)*8 + j][t*16 + (l&15)]
__global__ void prep(const float* __restrict__ W1, float* __restrict__ Wu,
                     short* __restrict__ Wfrag, float* __restrict__ out) {
    int idx = blockIdx.x * 256 + threadIdx.x;           // grid: 1408*256 = 360448
    if (idx < 32768) {
        Wu[idx] = W1[idx] - W1[idx + 256 * 256];
    } else if (idx < 98304) {
        int i = idx - 32768;
        int j = i & 7;
        int l = (i >> 3) & 63;
        int s = (i >> 9) & 7;
        int t = i >> 12;
        int k = s * 32 + ((l >> 4) << 3) + j;
        int n = t * 16 + (l & 15);
        float v;
        if (k < 128) v = W1[(128 + k) * 256 + n] + W1[(256 + k) * 256 + n];
        else         v = W1[(384 + (k - 128)) * 256 + n];
        Wfrag[i] = f2bf(v);
    } else {
        out[idx - 98304] = 0.f;                         // 262144 floats = 2048*128
    }
}

// Main fused kernel: 2 blocks per batch element (L-tile halves); 4 waves each.
// U[j]        = b1[j] + target[b] @ Wu[:,j]                        (f32, fused)
// h_pre[l][j] = U[j] + X[l] @ Wcat[:,j], X[l]=[item[l], item[l]*tgt] (bf16 MFMA)
// score[l]    = relu(h_pre[l]) @ W2 + b2
// out[b][d]  += sum_{l in this block's tiles, l<slen} score[l]*item[l][d]  (atomic)
// NOTE: __launch_bounds__ min-waves MUST stay 2 — forcing 4 caps VGPR at 128,
// spills the 128-reg bfrag array to scratch (R3: +430 MB HBM, 2x slower).
__launch_bounds__(256, 2)
__global__ void din_main(const float* __restrict__ target, const float* __restrict__ item_seq,
                         const int* __restrict__ seq_len, const float* __restrict__ W2,
                         const float* __restrict__ b2p, const short* __restrict__ Wfrag,
                         const float* __restrict__ Wu, const float* __restrict__ b1,
                         float* __restrict__ out) {
    const int bid = blockIdx.x;
    const int b = bid >> 1;
    const int half = bid & 1;
    const int tid = threadIdx.x;
    const int lane = tid & 63;
    const int wave = tid >> 6;
    const int col = lane & 15;   // MFMA C-layout col / B-frag n
    const int q = lane >> 4;     // quad: C rows q*4..q*4+3, A/B k-offset q*8

    const int slen = seq_len[b];
    const int nt = (slen + 15) >> 4;
    const int h0 = (nt + 1) >> 1;
    const int t0 = half ? h0 : 0;
    const int t1 = half ? nt : h0;
    if (t0 >= t1) return;        // uniform per block — safe early exit

    __shared__ __attribute__((aligned(16))) short Xl[16 * XSTRIDE];
    __shared__ __attribute__((aligned(16))) float tshared[128];
    __shared__ float u_s[256];
    __shared__ float w2_s[256];
    __shared__ float scoreP[4][16];
    __shared__ float out_s[128];

    const float b2 = b2p[0];

    // Staging assignment (fixed per thread): row r, cols c..c+7
    const int r = tid >> 4;
    const int c = (tid & 15) << 3;

    // ---- Prefetch first tile into registers (overlaps startup below) ----
    float4 v0, v1;
    {
        int lr = t0 * 16 + r;
        if (lr > 199) lr = 199;
        const float4* src = (const float4*)(item_seq + (((size_t)b * 200 + lr) * 128 + c));
        v0 = src[0]; v1 = src[1];
    }

    if (tid < 128) tshared[tid] = target[b * 128 + tid];
    w2_s[tid] = W2[tid];
    __syncthreads();

    // ---- Fused U: u_s[j] = b1[j] + sum_d tshared[d]*Wu[d*256+j] ----
    {
        float uacc = b1[tid];
#pragma unroll 8
        for (int d = 0; d < 128; ++d) uacc += tshared[d] * Wu[d * 256 + tid];
        u_s[tid] = uacc;
    }

    float tgt8[8];
    {
        const float4* t4 = (const float4*)(tshared + c);
        float4 ta = t4[0], tb = t4[1];
        tgt8[0] = ta.x; tgt8[1] = ta.y; tgt8[2] = ta.z; tgt8[3] = ta.w;
        tgt8[4] = tb.x; tgt8[5] = tb.y; tgt8[6] = tb.z; tgt8[7] = tb.w;
    }

    // ---- B fragments: this wave's 4 N-tiles × 8 K-steps, resident in registers ----
    short8 bfrag[4][8];
    {
        const short* base = Wfrag + ((size_t)(wave * 32) * 64 + lane) * 8;
#pragma unroll
        for (int i = 0; i < 4; i++)
#pragma unroll
            for (int s = 0; s < 8; s++)
                bfrag[i][s] = *(const short8*)(base + (size_t)((i * 8 + s) * 64) * 8);
    }

    float out_val = 0.f;
    f32x4 acc[4];

    for (int mt = t0; mt < t1; ++mt) {
        const int l0 = mt * 16;
        __syncthreads();  // previous tile's Xl readers done before restage

        // Pack prefetched registers -> Xl (item rows k 0..127, item*tgt k 128..255)
        {
            float v[8] = {v0.x, v0.y, v0.z, v0.w, v1.x, v1.y, v1.z, v1.w};
            short8 p0, p1;
#pragma unroll
            for (int i = 0; i < 8; i++) {
                p0[i] = f2bf(v[i]);
                p1[i] = f2bf(v[i] * tgt8[i]);
            }
            short* xr = Xl + r * XSTRIDE;
            *(short8*)(xr + c) = p0;
            *(short8*)(xr + 128 + c) = p1;
        }
        __syncthreads();

        // ---- Prefetch next tile (overlaps MFMA + epilogue) ----
        if (mt + 1 < t1) {
            int lr = l0 + 16 + r;
            if (lr > 199) lr = 199;     // clamped rows masked out later
            const float4* src = (const float4*)(item_seq + (((size_t)b * 200 + lr) * 128 + c));
            v0 = src[0]; v1 = src[1];
        }

#pragma unroll
        for (int i = 0; i < 4; i++) acc[i] = (f32x4){0.f, 0.f, 0.f, 0.f};

        const short* arow = Xl + col * XSTRIDE + q * 8;
#pragma unroll
        for (int s = 0; s < 8; s++) {
            short8 afrag = *(const short8*)(arow + s * 32);
#pragma unroll
            for (int i = 0; i < 4; i++)
                acc[i] = __builtin_amdgcn_mfma_f32_16x16x32_bf16(afrag, bfrag[i][s], acc[i], 0, 0, 0);
        }

        // Epilogue: relu + W2 partials. Lane holds (row=q*4+rg, col) of each tile.
        float sv[4] = {0.f, 0.f, 0.f, 0.f};
#pragma unroll
        for (int i = 0; i < 4; i++) {
            int j = (wave * 4 + i) * 16 + col;
            float uj = u_s[j], wj = w2_s[j];
#pragma unroll
            for (int rg = 0; rg < 4; rg++) {
                float h = acc[i][rg] + uj;
                h = h > 0.f ? h : 0.f;
                sv[rg] += h * wj;
            }
        }
#pragma unroll
        for (int off = 1; off < 16; off <<= 1) {
#pragma unroll
            for (int rg = 0; rg < 4; rg++) sv[rg] += __shfl_xor(sv[rg], off, 64);
        }
        if (col == 0) {
#pragma unroll
            for (int rg = 0; rg < 4; rg++) scoreP[wave][q * 4 + rg] = sv[rg];
        }
        __syncthreads();

        // out_val += sum_m score[m]*item[l0+m][d]; m-range split across thread halves
        {
            int d = tid & 127;
            int mbase = (tid >> 7) * 8;
#pragma unroll
            for (int mm = 0; mm < 8; mm++) {
                int m = mbase + mm;
                int l = l0 + m;
                float s = scoreP[0][m] + scoreP[1][m] + scoreP[2][m] + scoreP[3][m] + b2;
                s = (l < slen) ? s : 0.f;
                out_val += s * bf2f(Xl[m * XSTRIDE + d]);
            }
        }
    }

    __syncthreads();
    if (tid >= 128) out_s[tid - 128] = out_val;
    __syncthreads();
    if (tid < 128) atomicAdd(&out[b * 128 + tid], out_val + out_s[tid]);
}

extern "C" void kernel_launch(void* const* d_in, const int* in_sizes, int n_in,
                              void* d_out, int out_size, void* d_ws, size_t ws_size,
                              hipStream_t stream) {
    const float* target   = (const float*)d_in[0];
    const float* item_seq = (const float*)d_in[1];
    const int*   seq_len  = (const int*)d_in[2];
    const float* W1       = (const float*)d_in[3];
    const float* b1       = (const float*)d_in[4];
    const float* W2       = (const float*)d_in[5];
    const float* b2       = (const float*)d_in[6];
    float* out = (float*)d_out;

    char* ws = (char*)d_ws;
    float* Wu    = (float*)ws;                  // 128*256*4 = 131072 B
    short* Wfrag = (short*)(ws + 131072);       // 65536*2   = 131072 B

    prep<<<1408, 256, 0, stream>>>(W1, Wu, Wfrag, out);
    din_main<<<4096, 256, 0, stream>>>(target, item_seq, seq_len, W2, b2, Wfrag, Wu, b1, out);
}

// Round 5
// 339.915 us; speedup vs baseline: 1.5331x; 1.0289x over previous
//
#include <hip/hip_runtime.h>
#include <hip/hip_bf16.h>

typedef short short8 __attribute__((ext_vector_type(8)));
typedef float f32x4 __attribute__((ext_vector_type(4)));

#define XSTRIDE 264  // bf16 elements per LDS row: 256 + 8 pad

static __device__ inline short f2bf(float f) {
    unsigned u = __float_as_uint(f);
    unsigned r = (u + 0x7fffu + ((u >> 16) & 1u)) >> 16;
    return (short)r;
}
static __device__ inline float bf2f(short s) {
    return __uint_as_float(((unsigned)(unsigned short)s) << 16);
}

// prep: idx < 65536  -> Wfrag repack (Wcat -> MFMA B-fragment order, bf16)
//       else         -> zero d_out (2048*128 floats) for atomic accumulation
// Wcat[k][n]: k<128 -> W1b[k][n]+W1c[k][n];  k>=128 -> W1d[k-128][n]
// Wfrag[((t*8+s)*64+l)*8+j] = Wcat[s*32 + (l>>4)*8 + j][t*16 + (l&15)]
__global__ void prep(const float* __restrict__ W1, short* __restrict__ Wfrag,
                     float* __restrict__ out) {
    int idx = blockIdx.x * 256 + threadIdx.x;           // grid: 1280*256 = 327680
    if (idx < 65536) {
        int i = idx;
        int j = i & 7;
        int l = (i >> 3) & 63;
        int s = (i >> 9) & 7;
        int t = i >> 12;
        int k = s * 32 + ((l >> 4) << 3) + j;
        int n = t * 16 + (l & 15);
        float v;
        if (k < 128) v = W1[(128 + k) * 256 + n] + W1[(256 + k) * 256 + n];
        else         v = W1[(384 + (k - 128)) * 256 + n];
        Wfrag[i] = f2bf(v);
    } else {
        out[idx - 65536] = 0.f;                         // 262144 floats = 2048*128
    }
}

// U[b][j] = b1[j] + sum_d target[b][d] * (W1[d][j] - W1[256+d][j])
// 8 batch rows per block: each W1 column pair is loaded once, reused 8x.
__global__ void compute_u(const float* __restrict__ target, const float* __restrict__ W1,
                          const float* __restrict__ b1, float* __restrict__ U) {
    const int b8 = blockIdx.x;        // 256 blocks, rows b8*8 .. b8*8+7
    const int tid = threadIdx.x;      // j = tid (0..255)
    __shared__ float tl[1024];        // 8 rows x 128
#pragma unroll
    for (int k = 0; k < 4; k++) tl[k * 256 + tid] = target[b8 * 1024 + k * 256 + tid];
    __syncthreads();
    float acc[8] = {0.f, 0.f, 0.f, 0.f, 0.f, 0.f, 0.f, 0.f};
#pragma unroll 8
    for (int d = 0; d < 128; ++d) {
        float wud = W1[d * 256 + tid] - W1[(256 + d) * 256 + tid];
#pragma unroll
        for (int r = 0; r < 8; r++) acc[r] += tl[r * 128 + d] * wud;
    }
    float bj = b1[tid];
#pragma unroll
    for (int r = 0; r < 8; r++) U[(b8 * 8 + r) * 256 + tid] = acc[r] + bj;
}

// Main fused kernel: 2 blocks per batch element (L-tile halves); 8 waves (512 thr).
// Wave w owns n-cols [w*32, w*32+32) (2 MFMA n-tiles) -> bfrag only 32 VGPR/lane.
// h_pre[l][j] = U[j] + X[l] @ Wcat[:,j], X[l]=[item[l], item[l]*tgt] (bf16 MFMA)
// score[l]    = relu(h_pre[l]) @ W2 + b2
// out[b][d]  += sum_{l in tiles, l<slen} score[l]*item[l][d]  (atomic)
// NOTE (R3 lesson): VGPR cap must stay >= ~110 or bfrag spills to scratch.
// (512,4) -> cap 128; measured need ~95.
__launch_bounds__(512, 4)
__global__ void din_main(const float* __restrict__ target, const float* __restrict__ item_seq,
                         const int* __restrict__ seq_len, const float* __restrict__ W2,
                         const float* __restrict__ b2p, const short* __restrict__ Wfrag,
                         const float* __restrict__ U, float* __restrict__ out) {
    const int bid = blockIdx.x;
    const int b = bid >> 1;
    const int half = bid & 1;
    const int tid = threadIdx.x;
    const int lane = tid & 63;
    const int wave = tid >> 6;   // 0..7
    const int col = lane & 15;   // MFMA C-layout col / B-frag n
    const int q = lane >> 4;     // quad

    const int slen = seq_len[b];
    const int nt = (slen + 15) >> 4;
    const int h0 = (nt + 1) >> 1;
    const int t0 = half ? h0 : 0;
    const int t1 = half ? nt : h0;
    if (t0 >= t1) return;        // uniform per block

    __shared__ __attribute__((aligned(16))) short Xl[2][16 * XSTRIDE];  // double buffer
    __shared__ __attribute__((aligned(16))) float scoreP[16][8];        // [row m][wave]
    __shared__ float out_s[3][128];

    const float b2 = b2p[0];

    // Staging assignment: row r (0..15), 8 bf16 cols at c8; cl = source item col
    const int r = tid >> 5;
    const int c8 = (tid & 31) << 3;
    const int cl = c8 & 127;
    const bool dotpart = (c8 >= 128);

    float tgt8[8];
    {
        const float4* t4 = (const float4*)(target + b * 128 + cl);
        float4 ta = t4[0], tb = t4[1];
        tgt8[0] = ta.x; tgt8[1] = ta.y; tgt8[2] = ta.z; tgt8[3] = ta.w;
        tgt8[4] = tb.x; tgt8[5] = tb.y; tgt8[6] = tb.z; tgt8[7] = tb.w;
    }

    // Per-lane epilogue constants: j_i = (wave*2+i)*16 + col
    const int j0 = (wave * 2 + 0) * 16 + col;
    const int j1 = (wave * 2 + 1) * 16 + col;
    const float u0 = U[b * 256 + j0], u1 = U[b * 256 + j1];
    const float w20 = W2[j0], w21 = W2[j1];

    // B fragments: this wave's 2 N-tiles x 8 K-steps in registers (32 VGPR)
    short8 bfrag[2][8];
    {
        const short* base = Wfrag + ((size_t)(wave * 16) * 64 + lane) * 8;
#pragma unroll
        for (int i = 0; i < 2; i++)
#pragma unroll
            for (int s = 0; s < 8; s++)
                bfrag[i][s] = *(const short8*)(base + (size_t)((i * 8 + s) * 64) * 8);
    }

    // Prefetch first tile (8 floats/thread)
    float4 v0, v1;
    {
        int lr = t0 * 16 + r;
        if (lr > 199) lr = 199;
        const float4* src = (const float4*)(item_seq + (((size_t)b * 200 + lr) * 128 + cl));
        v0 = src[0]; v1 = src[1];
    }

    const int d = tid & 127;
    const int g = tid >> 7;      // 0..3 (m-group for out accumulation)
    float out_val = 0.f;
    f32x4 acc[2];

    for (int mt = t0; mt < t1; ++mt) {
        const int l0 = mt * 16;
        short* xb = Xl[mt & 1];

        // Pack prefetched regs -> Xl buffer (one short8 store per thread)
        {
            float v[8] = {v0.x, v0.y, v0.z, v0.w, v1.x, v1.y, v1.z, v1.w};
            short8 p;
            if (dotpart) {
#pragma unroll
                for (int i = 0; i < 8; i++) p[i] = f2bf(v[i] * tgt8[i]);
            } else {
#pragma unroll
                for (int i = 0; i < 8; i++) p[i] = f2bf(v[i]);
            }
            *(short8*)(xb + r * XSTRIDE + c8) = p;
        }
        __syncthreads();   // Xl[cur] written; scoreP of prev tile fully read

        // Prefetch next tile (overlaps MFMA + epilogue)
        if (mt + 1 < t1) {
            int lr = l0 + 16 + r;
            if (lr > 199) lr = 199;
            const float4* src = (const float4*)(item_seq + (((size_t)b * 200 + lr) * 128 + cl));
            v0 = src[0]; v1 = src[1];
        }

        acc[0] = (f32x4){0.f, 0.f, 0.f, 0.f};
        acc[1] = (f32x4){0.f, 0.f, 0.f, 0.f};
        const short* arow = xb + col * XSTRIDE + q * 8;
#pragma unroll
        for (int s = 0; s < 8; s++) {
            short8 afrag = *(const short8*)(arow + s * 32);
            acc[0] = __builtin_amdgcn_mfma_f32_16x16x32_bf16(afrag, bfrag[0][s], acc[0], 0, 0, 0);
            acc[1] = __builtin_amdgcn_mfma_f32_16x16x32_bf16(afrag, bfrag[1][s], acc[1], 0, 0, 0);
        }

        // Epilogue: relu + W2 partial over this wave's 32 cols, reduce 16 lanes
        float sv[4];
#pragma unroll
        for (int rg = 0; rg < 4; rg++) {
            float ha = acc[0][rg] + u0; ha = ha > 0.f ? ha : 0.f;
            float hb = acc[1][rg] + u1; hb = hb > 0.f ? hb : 0.f;
            sv[rg] = ha * w20 + hb * w21;
        }
#pragma unroll
        for (int off = 1; off < 16; off <<= 1) {
#pragma unroll
            for (int rg = 0; rg < 4; rg++) sv[rg] += __shfl_xor(sv[rg], off, 64);
        }
        if (col == 0) {
#pragma unroll
            for (int rg = 0; rg < 4; rg++) scoreP[q * 4 + rg][wave] = sv[rg];
        }
        __syncthreads();   // scoreP written; Xl[cur] MFMA reads done

        // out_val += score[m] * item[l0+m][d]; 4 m per thread group
#pragma unroll
        for (int mm = 0; mm < 4; mm++) {
            int m = g * 4 + mm;
            int l = l0 + m;
            const float4* sp = (const float4*)&scoreP[m][0];
            float4 s0 = sp[0], s1 = sp[1];
            float s = ((s0.x + s0.y) + (s0.z + s0.w)) + ((s1.x + s1.y) + (s1.z + s1.w)) + b2;
            s = (l < slen) ? s : 0.f;
            out_val += s * bf2f(xb[m * XSTRIDE + d]);
        }
    }

    __syncthreads();
    if (g > 0) out_s[g - 1][d] = out_val;
    __syncthreads();
    if (g == 0) atomicAdd(&out[b * 128 + d], out_val + out_s[0][d] + out_s[1][d] + out_s[2][d]);
}

extern "C" void kernel_launch(void* const* d_in, const int* in_sizes, int n_in,
                              void* d_out, int out_size, void* d_ws, size_t ws_size,
                              hipStream_t stream) {
    const float* target   = (const float*)d_in[0];
    const float* item_seq = (const float*)d_in[1];
    const int*   seq_len  = (const int*)d_in[2];
    const float* W1       = (const float*)d_in[3];
    const float* b1       = (const float*)d_in[4];
    const float* W2       = (const float*)d_in[5];
    const float* b2       = (const float*)d_in[6];
    float* out = (float*)d_out;

    char* ws = (char*)d_ws;
    short* Wfrag = (short*)ws;                  // 65536*2    = 131072 B
    float* U     = (float*)(ws + 131072);       // 2048*256*4 = 2097152 B

    prep<<<1280, 256, 0, stream>>>(W1, Wfrag, out);
    compute_u<<<256, 256, 0, stream>>>(target, W1, b1, U);
    din_main<<<4096, 512, 0, stream>>>(target, item_seq, seq_len, W2, b2, Wfrag, U, out);
}

// Round 6
// 312.336 us; speedup vs baseline: 1.6685x; 1.0883x over previous
//
#include <hip/hip_runtime.h>
#include <hip/hip_bf16.h>

typedef short short8 __attribute__((ext_vector_type(8)));
typedef float f32x4 __attribute__((ext_vector_type(4)));

#define XS 136  // Xl row stride in bf16 elems: 128 + 8 pad (272 B/row -> 4-bank rotation)

static __device__ inline short f2bf(float f) {
    unsigned u = __float_as_uint(f);
    unsigned r = (u + 0x7fffu + ((u >> 16) & 1u)) >> 16;
    return (short)r;
}
static __device__ inline float bf2f(short s) {
    return __uint_as_float(((unsigned)(unsigned short)s) << 16);
}

// prep: build two 128x256 bf16 fragment arrays in MFMA B-layout (16x16x32):
//   Wbc[k][n] = W1b[k][n] + W1c[k][n]     (item coefficient)
//   Wd [k][n] = W1d[k][n]                 (dot coefficient, combined per-b later)
// frag[((t*4+s)*64+l)*8+j] = src[s*32 + (l>>4)*8 + j][t*16 + (l&15)], t in 0..15, s in 0..3
__global__ void prep(const float* __restrict__ W1, short* __restrict__ Wbc,
                     short* __restrict__ Wd) {
    int idx = blockIdx.x * 256 + threadIdx.x;    // 256 blocks -> 65536 threads
    int half = idx >> 15;
    int i = idx & 32767;
    int j = i & 7;
    int l = (i >> 3) & 63;
    int s = (i >> 9) & 3;
    int t = i >> 11;
    int k = s * 32 + ((l >> 4) << 3) + j;
    int n = t * 16 + (l & 15);
    if (half == 0) Wbc[i] = f2bf(W1[(128 + k) * 256 + n] + W1[(256 + k) * 256 + n]);
    else           Wd[i]  = f2bf(W1[(384 + k) * 256 + n]);
}

// U[b][j] = b1[j] + sum_d target[b][d] * (W1a[d][j] - W1c[d][j]);  8 b-rows/block for W1 reuse
__global__ void compute_u(const float* __restrict__ target, const float* __restrict__ W1,
                          const float* __restrict__ b1, float* __restrict__ U) {
    const int b8 = blockIdx.x;        // 256 blocks
    const int tid = threadIdx.x;      // j
    __shared__ float tl[1024];        // 8 rows x 128
#pragma unroll
    for (int k = 0; k < 4; k++) tl[k * 256 + tid] = target[b8 * 1024 + k * 256 + tid];
    __syncthreads();
    float acc[8] = {0.f, 0.f, 0.f, 0.f, 0.f, 0.f, 0.f, 0.f};
#pragma unroll 8
    for (int d = 0; d < 128; ++d) {
        float wud = W1[d * 256 + tid] - W1[(256 + d) * 256 + tid];
#pragma unroll
        for (int r = 0; r < 8; r++) acc[r] += tl[r * 128 + d] * wud;
    }
    float bj = b1[tid];
#pragma unroll
    for (int r = 0; r < 8; r++) U[(b8 * 8 + r) * 256 + tid] = acc[r] + bj;
}

// Main fused kernel: one block per batch b; 4 waves; wave w owns n-tiles w*4..w*4+3.
// Weff_b[k][j] = Wbc[k][j] + tgt[k]*Wd[k][j]  (built once per block into registers, bf16)
// h_pre[l][j]  = U[j] + item[l] @ Weff_b      (K=128 bf16 MFMA)
// score[l]     = relu(h_pre[l]) @ W2 + b2;  out[b][d] = sum_{l<slen} score[l]*item[l][d]
// NOTE (R3 lesson): don't force min-waves 4 — VGPR cap would spill bfrag.
__launch_bounds__(256, 2)
__global__ void din_main(const float* __restrict__ target, const float* __restrict__ item_seq,
                         const int* __restrict__ seq_len, const float* __restrict__ W2,
                         const float* __restrict__ b2p, const short* __restrict__ Wbc,
                         const short* __restrict__ Wd, const float* __restrict__ U,
                         float* __restrict__ out) {
    const int b = blockIdx.x;
    const int tid = threadIdx.x;
    const int lane = tid & 63;
    const int w = tid >> 6;      // wave 0..3
    const int col = lane & 15;   // MFMA C col / B-frag n
    const int q = lane >> 4;     // quad

    const int slen = seq_len[b];
    const int nt = (slen + 15) >> 4;

    __shared__ __attribute__((aligned(16))) short Xl[2][16 * XS];  // double buffer, 8.7 KB
    __shared__ __attribute__((aligned(16))) float tsh[128];
    __shared__ float u_s[256];
    __shared__ float w2_s[256];
    __shared__ __attribute__((aligned(16))) float scoreP[16][4];
    __shared__ float out_s[128];

    // Staging assignment: row r (0..15), 8 cols at c
    const int r = tid >> 4;
    const int c = (tid & 15) << 3;

    // Prefetch tile 0 (rows 0..15 always in-bounds)
    float4 v0, v1;
    {
        const float4* src = (const float4*)(item_seq + (((size_t)b * 200 + r) * 128 + c));
        v0 = src[0]; v1 = src[1];
    }

    if (tid < 128) tsh[tid] = target[b * 128 + tid];
    u_s[tid] = U[b * 256 + tid];
    w2_s[tid] = W2[tid];
    const float b2 = b2p[0];
    __syncthreads();

    // ---- Build per-batch Weff B-fragments in registers: 4 n-tiles x 4 K-steps ----
    short8 bfrag[4][4];
#pragma unroll
    for (int s = 0; s < 4; s++) {
        const float4* tp = (const float4*)(tsh + s * 32 + q * 8);
        float4 ta = tp[0], tb = tp[1];
        float tk[8] = {ta.x, ta.y, ta.z, ta.w, tb.x, tb.y, tb.z, tb.w};
#pragma unroll
        for (int i = 0; i < 4; i++) {
            size_t off = ((size_t)((w * 4 + i) * 4 + s) * 64 + lane) * 8;
            short8 bc = *(const short8*)(Wbc + off);
            short8 dd = *(const short8*)(Wd + off);
            short8 e;
#pragma unroll
            for (int j = 0; j < 8; j++) e[j] = f2bf(bf2f(bc[j]) + tk[j] * bf2f(dd[j]));
            bfrag[i][s] = e;
        }
    }

    // Per-lane epilogue constants
    float u_c[4], w2c[4];
#pragma unroll
    for (int i = 0; i < 4; i++) {
        int j = (w * 4 + i) * 16 + col;
        u_c[i] = u_s[j];
        w2c[i] = w2_s[j];
    }

    const int d = tid & 127;
    const int g = tid >> 7;      // 0/1: m-half for out accumulation
    float out_val = 0.f;
    f32x4 acc[4];

    for (int mt = 0; mt < nt; ++mt) {
        const int l0 = mt * 16;
        short* xb = Xl[mt & 1];

        // Pack prefetched item rows -> bf16 LDS (no dot channel needed)
        {
            float v[8] = {v0.x, v0.y, v0.z, v0.w, v1.x, v1.y, v1.z, v1.w};
            short8 p;
#pragma unroll
            for (int j = 0; j < 8; j++) p[j] = f2bf(v[j]);
            *(short8*)(xb + r * XS + c) = p;
        }
        __syncthreads();   // sync#1: Xl[cur] visible

        // Prefetch next tile (overlaps MFMA + epilogue)
        if (mt + 1 < nt) {
            int lr = l0 + 16 + r;
            if (lr > 199) lr = 199;   // clamp: masked out later, stays in-bounds
            const float4* src = (const float4*)(item_seq + (((size_t)b * 200 + lr) * 128 + c));
            v0 = src[0]; v1 = src[1];
        }

#pragma unroll
        for (int i = 0; i < 4; i++) acc[i] = (f32x4){0.f, 0.f, 0.f, 0.f};
        const short* arow = xb + col * XS + q * 8;
#pragma unroll
        for (int s = 0; s < 4; s++) {
            short8 af = *(const short8*)(arow + s * 32);
#pragma unroll
            for (int i = 0; i < 4; i++)
                acc[i] = __builtin_amdgcn_mfma_f32_16x16x32_bf16(af, bfrag[i][s], acc[i], 0, 0, 0);
        }

        // Epilogue: relu + W2 partial over this wave's 64 cols; reduce 16 lanes
        float sv[4];
#pragma unroll
        for (int rg = 0; rg < 4; rg++) {
            float s0 = 0.f;
#pragma unroll
            for (int i = 0; i < 4; i++) {
                float h = acc[i][rg] + u_c[i];
                h = h > 0.f ? h : 0.f;
                s0 += h * w2c[i];
            }
            sv[rg] = s0;
        }
#pragma unroll
        for (int off = 1; off < 16; off <<= 1) {
#pragma unroll
            for (int rg = 0; rg < 4; rg++) sv[rg] += __shfl_xor(sv[rg], off, 64);
        }
        if (col == 0) {
#pragma unroll
            for (int rg = 0; rg < 4; rg++) scoreP[q * 4 + rg][w] = sv[rg];
        }
        __syncthreads();   // sync#2: scoreP visible; Xl[cur] MFMA reads done

        // out_val += score[m] * item[l0+m][d]; 8 m's per thread half
#pragma unroll
        for (int mm = 0; mm < 8; mm++) {
            int m = g * 8 + mm;
            int l = l0 + m;
            float4 sp = *(const float4*)&scoreP[m][0];
            float s = (sp.x + sp.y) + (sp.z + sp.w) + b2;
            s = (l < slen) ? s : 0.f;
            out_val += s * bf2f(xb[m * XS + d]);
        }
    }

    __syncthreads();
    if (g == 1) out_s[d] = out_val;
    __syncthreads();
    if (g == 0) out[b * 128 + d] = out_val + out_s[d];   // direct write, no atomics
}

extern "C" void kernel_launch(void* const* d_in, const int* in_sizes, int n_in,
                              void* d_out, int out_size, void* d_ws, size_t ws_size,
                              hipStream_t stream) {
    const float* target   = (const float*)d_in[0];
    const float* item_seq = (const float*)d_in[1];
    const int*   seq_len  = (const int*)d_in[2];
    const float* W1       = (const float*)d_in[3];
    const float* b1       = (const float*)d_in[4];
    const float* W2       = (const float*)d_in[5];
    const float* b2       = (const float*)d_in[6];
    float* out = (float*)d_out;

    char* ws = (char*)d_ws;
    short* Wbc = (short*)ws;                    // 32768*2 = 65536 B
    short* Wd  = (short*)(ws + 65536);          // 65536 B
    float* U   = (float*)(ws + 131072);         // 2048*256*4 = 2 MB

    prep<<<256, 256, 0, stream>>>(W1, Wbc, Wd);
    compute_u<<<256, 256, 0, stream>>>(target, W1, b1, U);
    din_main<<<2048, 256, 0, stream>>>(target, item_seq, seq_len, W2, b2, Wbc, Wd, U, out);
}